// Round 5
// baseline (257.167 us; speedup 1.0000x reference)
//
#include <hip/hip_runtime.h>
#include <hip/hip_bf16.h>

#define N_NODES 50000
#define N_EDGES 800000
#define C 128

#define NBB   391      // buckets of 128 nodes: bucket = dst >> 7
#define CAPB  2600     // per-bucket capacity (mean 2048, +12 sigma)
#define CHUNK 4096     // edges per binA block

// ---------------------------------------------------------------------------
// k_binA: single-level radix partition. Each block takes CHUNK edges,
// histograms by bucket (dst>>7) in LDS, scatters locally in LDS, reserves a
// per-bucket run with ONE global atomic per bucket, writes runs coalesced
// into tmp (bucket-strided: bucket b owns [b*CAPB, (b+1)*CAPB)).
// ---------------------------------------------------------------------------
__global__ __launch_bounds__(256) void k_binA(const int* __restrict__ ei,
                                              int* __restrict__ gcur,
                                              int2* __restrict__ tmp) {
    __shared__ int hist[NBB];
    __shared__ int lbase[NBB];
    __shared__ int gbaseL[NBB];
    __shared__ int stmp[256];
    __shared__ int2 buf[CHUNK];
    __shared__ int totalv;

    int tid = threadIdx.x;
    int e0 = blockIdx.x * CHUNK;

    for (int i = tid; i < NBB; i += 256) hist[i] = 0;
    __syncthreads();

    int sarr[16], darr[16], parr[16];
#pragma unroll
    for (int j = 0; j < 16; ++j) {
        int e = e0 + j * 256 + tid;
        darr[j] = -1;
        if (e < N_EDGES) {
            sarr[j] = ei[e];
            int d = ei[N_EDGES + e];
            darr[j] = d;
            parr[j] = atomicAdd(&hist[d >> 7], 1);
        }
    }
    __syncthreads();

    // exclusive scan of hist (pairs: thread t owns buckets 2t, 2t+1)
    {
        int i0 = 2 * tid, i1 = 2 * tid + 1;
        int c0 = (i0 < NBB) ? hist[i0] : 0;
        int c1 = (i1 < NBB) ? hist[i1] : 0;
        int c = c0 + c1;
        stmp[tid] = c;
        __syncthreads();
        int v = c;
        for (int d = 1; d < 256; d <<= 1) {
            int w = (tid >= d) ? stmp[tid - d] : 0;
            __syncthreads();
            v += w;
            stmp[tid] = v;
            __syncthreads();
        }
        int excl = v - c;
        if (i0 < NBB) lbase[i0] = excl;
        if (i1 < NBB) lbase[i1] = excl + c0;
        if (tid == 255) totalv = v;
    }
    // reserve global runs (one atomic per non-empty bucket per block)
    for (int i = tid; i < NBB; i += 256) {
        int cnt = hist[i];
        int run = (cnt > 0) ? atomicAdd(&gcur[i], cnt) : 0;
        gbaseL[i] = i * CAPB + run;
    }
    __syncthreads();

    // LDS scatter
#pragma unroll
    for (int j = 0; j < 16; ++j) {
        if (darr[j] >= 0) {
            int b = darr[j] >> 7;
            buf[lbase[b] + parr[j]] = make_int2(sarr[j], darr[j]);
        }
    }
    __syncthreads();

    // coalesced write-out of per-bucket runs
    int total = totalv;
    for (int i = tid; i < total; i += 256) {
        int2 v = buf[i];
        int b = v.y >> 7;
        int gpos = gbaseL[b] + (i - lbase[b]);
        if (gpos < (b + 1) * CAPB) tmp[gpos] = v;   // overflow safety
    }
}

// ---------------------------------------------------------------------------
// k_dinv: per-node in-degree from the bucket, write dinv = rsqrt(deg+1).
// ---------------------------------------------------------------------------
__global__ __launch_bounds__(256) void k_dinv(const int2* __restrict__ tmp,
                                              const int* __restrict__ gcur,
                                              float* __restrict__ dinv) {
    __shared__ int cnt[128];
    int b = blockIdx.x, tid = threadIdx.x;
    if (tid < 128) cnt[tid] = 0;
    __syncthreads();
    int n = gcur[b];
    if (n > CAPB) n = CAPB;
    for (int i = tid; i < n; i += 256)
        atomicAdd(&cnt[tmp[b * CAPB + i].y & 127], 1);
    __syncthreads();
    int node = b * 128 + tid;
    if (tid < 128 && node < N_NODES)
        dinv[node] = rsqrtf((float)cnt[tid] + 1.0f);
}

// ---------------------------------------------------------------------------
// bf16 pack helpers (RTN)
// ---------------------------------------------------------------------------
__device__ __forceinline__ unsigned int bf16rtn(float f) {
    unsigned int u = __float_as_uint(f);
    return (u + 0x7fffu + ((u >> 16) & 1u)) >> 16;
}
__device__ __forceinline__ unsigned int packbf2(float lo, float hi) {
    return bf16rtn(lo) | (bf16rtn(hi) << 16);
}

// ---------------------------------------------------------------------------
// f32 GEMM -> bf16 out (unchanged from round 3/4): 64x128 tile, 256 thr,
// K-panels of 32 in LDS, per-thread 4 rows x 8 cols.
// ---------------------------------------------------------------------------
#define XS_STRIDE 44

template <bool RELU>
__global__ __launch_bounds__(256, 2) void k_gemm(const float* __restrict__ A,
                                                 const float* __restrict__ W,
                                                 unsigned int* __restrict__ Hout) {
    __shared__ float Wp[32 * 128];
    __shared__ float Xs[64 * XS_STRIDE];
    int tid = threadIdx.x;
    int cg = tid & 15;
    int rg = tid >> 4;
    int row0 = blockIdx.x * 64;

    const float4* W4 = (const float4*)W;
    const float4* A4 = (const float4*)A;
    float4* Wp4 = (float4*)Wp;

    float4 acc[4][2];
#pragma unroll
    for (int i = 0; i < 4; ++i) {
        acc[i][0] = make_float4(0.f, 0.f, 0.f, 0.f);
        acc[i][1] = make_float4(0.f, 0.f, 0.f, 0.f);
    }

    for (int p = 0; p < 4; ++p) {
        if (p) __syncthreads();
#pragma unroll
        for (int i = 0; i < 4; ++i)
            Wp4[tid + 256 * i] = W4[p * 1024 + tid + 256 * i];
#pragma unroll
        for (int i = 0; i < 2; ++i) {
            int idx = tid + 256 * i;
            int r = idx >> 3, c4 = idx & 7;
            int gr = row0 + r;
            float4 v = make_float4(0.f, 0.f, 0.f, 0.f);
            if (gr < N_NODES) v = A4[gr * 32 + p * 8 + c4];
            if (RELU) {
                v.x = fmaxf(v.x, 0.f); v.y = fmaxf(v.y, 0.f);
                v.z = fmaxf(v.z, 0.f); v.w = fmaxf(v.w, 0.f);
            }
            *(float4*)(Xs + r * XS_STRIDE + c4 * 4) = v;
        }
        __syncthreads();

#pragma unroll
        for (int k0 = 0; k0 < 32; k0 += 4) {
            float4 wv[4][2];
#pragma unroll
            for (int kk = 0; kk < 4; ++kk) {
                wv[kk][0] = Wp4[(k0 + kk) * 32 + cg];
                wv[kk][1] = Wp4[(k0 + kk) * 32 + 16 + cg];
            }
            float4 xv[4];
#pragma unroll
            for (int i = 0; i < 4; ++i)
                xv[i] = *(const float4*)(Xs + (rg * 4 + i) * XS_STRIDE + k0);
#pragma unroll
            for (int i = 0; i < 4; ++i) {
#pragma unroll
                for (int kk = 0; kk < 4; ++kk) {
                    float xs = (kk == 0) ? xv[i].x : (kk == 1) ? xv[i].y
                             : (kk == 2) ? xv[i].z : xv[i].w;
#pragma unroll
                    for (int h = 0; h < 2; ++h) {
                        acc[i][h].x += xs * wv[kk][h].x;
                        acc[i][h].y += xs * wv[kk][h].y;
                        acc[i][h].z += xs * wv[kk][h].z;
                        acc[i][h].w += xs * wv[kk][h].w;
                    }
                }
            }
        }
    }

#pragma unroll
    for (int i = 0; i < 4; ++i) {
        int gr = row0 + rg * 4 + i;
        if (gr < N_NODES) {
            uint2 u0, u1;
            u0.x = packbf2(acc[i][0].x, acc[i][0].y);
            u0.y = packbf2(acc[i][0].z, acc[i][0].w);
            u1.x = packbf2(acc[i][1].x, acc[i][1].y);
            u1.y = packbf2(acc[i][1].z, acc[i][1].w);
            *(uint2*)&Hout[gr * 64 + cg * 2]      = u0;
            *(uint2*)&Hout[gr * 64 + 32 + cg * 2] = u1;
        }
    }
}

// ---------------------------------------------------------------------------
// Fused bucket aggregation: block = 512 thr (8 waves) per 128-node bucket.
// Stage bucket edges from tmp into LDS, build block-local CSR (LDS count +
// scan + scatter), then each wave aggregates 16 nodes: gather bf16 h rows
// (eg=lane>>4 edge group, cq=lane&15 channel quad). No global CSR arrays.
// FINAL fuses relu + 128->1 linear.
// ---------------------------------------------------------------------------
__device__ __forceinline__ void accum8(float* acc, float d, uint4 u) {
    acc[0] += d * __uint_as_float(u.x << 16);
    acc[1] += d * __uint_as_float(u.x & 0xffff0000u);
    acc[2] += d * __uint_as_float(u.y << 16);
    acc[3] += d * __uint_as_float(u.y & 0xffff0000u);
    acc[4] += d * __uint_as_float(u.z << 16);
    acc[5] += d * __uint_as_float(u.z & 0xffff0000u);
    acc[6] += d * __uint_as_float(u.w << 16);
    acc[7] += d * __uint_as_float(u.w & 0xffff0000u);
}

template <bool FINAL>
__global__ __launch_bounds__(512) void k_agg(const uint4* __restrict__ h4,
                                             const int2* __restrict__ tmp,
                                             const int* __restrict__ gcur,
                                             const float* __restrict__ dinv,
                                             const float* __restrict__ bias,
                                             const float* __restrict__ Wlin,
                                             const float* __restrict__ blin,
                                             float* __restrict__ aggout) {
    __shared__ int   rawsrc[CAPB];
    __shared__ short rawloc[CAPB];
    __shared__ int   lcsr[CAPB];
    __shared__ int   lcnt[128];
    __shared__ int   lbase0[128];
    __shared__ int   lcur[128];
    __shared__ int   stmp[128];

    int b = blockIdx.x, tid = threadIdx.x;
    int cnt = gcur[b];
    if (cnt > CAPB) cnt = CAPB;

    if (tid < 128) { lcnt[tid] = 0; lcur[tid] = 0; }
    __syncthreads();

    for (int i = tid; i < cnt; i += 512) {
        int2 v = tmp[b * CAPB + i];
        int l = v.y & 127;
        rawsrc[i] = v.x;
        rawloc[i] = (short)l;
        atomicAdd(&lcnt[l], 1);
    }
    __syncthreads();

    // exclusive scan of lcnt -> lbase0 (Hillis-Steele over 128)
    {
        int c = (tid < 128) ? lcnt[tid] : 0;
        if (tid < 128) stmp[tid] = c;
        __syncthreads();
        int v = c;
        for (int d = 1; d < 128; d <<= 1) {
            int w = (tid >= d && tid < 128) ? stmp[tid - d] : 0;
            __syncthreads();
            if (tid < 128) { v += w; stmp[tid] = v; }
            __syncthreads();
        }
        if (tid < 128) lbase0[tid] = v - c;
    }
    __syncthreads();

    for (int i = tid; i < cnt; i += 512) {
        int l = rawloc[i];
        int p = atomicAdd(&lcur[l], 1);
        lcsr[lbase0[l] + p] = rawsrc[i];
    }
    __syncthreads();

    int wv = tid >> 6, lane = tid & 63, eg = lane >> 4, cq = lane & 15;

    // hoisted per-lane constants
    float4 bv0 = ((const float4*)bias)[cq * 2];
    float4 bv1 = ((const float4*)bias)[cq * 2 + 1];
    float4 wl0 = make_float4(0.f, 0.f, 0.f, 0.f), wl1 = wl0;
    float bl = 0.f;
    if (FINAL) {
        wl0 = ((const float4*)Wlin)[cq * 2];
        wl1 = ((const float4*)Wlin)[cq * 2 + 1];
        bl = blin[0];
    }

    for (int t = 0; t < 16; ++t) {
        int ln = wv * 16 + t;
        int node = b * 128 + ln;
        if (node >= N_NODES) break;   // uniform per wave
        int deg = lcnt[ln];
        int o0 = lbase0[ln], o1 = o0 + deg;

        float acc[8];
#pragma unroll
        for (int j = 0; j < 8; ++j) acc[j] = 0.f;

        int e = o0;
        for (; e + 8 <= o1; e += 8) {
            int s0 = lcsr[e + 2 * eg];
            int s1 = lcsr[e + 2 * eg + 1];
            float d0 = dinv[s0], d1 = dinv[s1];
            uint4 u0 = h4[s0 * 16 + cq];
            uint4 u1 = h4[s1 * 16 + cq];
            accum8(acc, d0, u0);
            accum8(acc, d1, u1);
        }
        {   // tail (< 8 edges): group eg takes e+2eg, e+2eg+1 if in range
            int r = o1 - e;
            int b0 = e + 2 * eg;
            if (2 * eg < r)     { int s = lcsr[b0];     accum8(acc, dinv[s], h4[s * 16 + cq]); }
            if (2 * eg + 1 < r) { int s = lcsr[b0 + 1]; accum8(acc, dinv[s], h4[s * 16 + cq]); }
        }
        // combine edge groups
#pragma unroll
        for (int j = 0; j < 8; ++j) {
            acc[j] += __shfl_xor(acc[j], 16, 64);
            acc[j] += __shfl_xor(acc[j], 32, 64);
        }

        float dv = rsqrtf((float)deg + 1.0f);
        float dv2 = dv * dv;
        uint4 us = h4[node * 16 + cq];
        float hv[8];
        hv[0] = __uint_as_float(us.x << 16); hv[1] = __uint_as_float(us.x & 0xffff0000u);
        hv[2] = __uint_as_float(us.y << 16); hv[3] = __uint_as_float(us.y & 0xffff0000u);
        hv[4] = __uint_as_float(us.z << 16); hv[5] = __uint_as_float(us.z & 0xffff0000u);
        hv[6] = __uint_as_float(us.w << 16); hv[7] = __uint_as_float(us.w & 0xffff0000u);
        float o[8];
        o[0] = dv * acc[0] + dv2 * hv[0] + bv0.x;
        o[1] = dv * acc[1] + dv2 * hv[1] + bv0.y;
        o[2] = dv * acc[2] + dv2 * hv[2] + bv0.z;
        o[3] = dv * acc[3] + dv2 * hv[3] + bv0.w;
        o[4] = dv * acc[4] + dv2 * hv[4] + bv1.x;
        o[5] = dv * acc[5] + dv2 * hv[5] + bv1.y;
        o[6] = dv * acc[6] + dv2 * hv[6] + bv1.z;
        o[7] = dv * acc[7] + dv2 * hv[7] + bv1.w;

        if (!FINAL) {
            if (eg == 0) {
                float4* out4 = (float4*)aggout;
                out4[node * 32 + cq * 2]     = make_float4(o[0], o[1], o[2], o[3]);
                out4[node * 32 + cq * 2 + 1] = make_float4(o[4], o[5], o[6], o[7]);
            }
        } else {
            float v = fmaxf(o[0], 0.f) * wl0.x + fmaxf(o[1], 0.f) * wl0.y
                    + fmaxf(o[2], 0.f) * wl0.z + fmaxf(o[3], 0.f) * wl0.w
                    + fmaxf(o[4], 0.f) * wl1.x + fmaxf(o[5], 0.f) * wl1.y
                    + fmaxf(o[6], 0.f) * wl1.z + fmaxf(o[7], 0.f) * wl1.w;
            v += __shfl_xor(v, 1, 64);
            v += __shfl_xor(v, 2, 64);
            v += __shfl_xor(v, 4, 64);
            v += __shfl_xor(v, 8, 64);
            if (lane == 0) aggout[node] = v + bl;
        }
    }
}

// ---------------------------------------------------------------------------
extern "C" void kernel_launch(void* const* d_in, const int* in_sizes, int n_in,
                              void* d_out, int out_size, void* d_ws, size_t ws_size,
                              hipStream_t stream) {
    const float* x    = (const float*)d_in[0];
    const int*   ei   = (const int*)d_in[2];
    const float* W1   = (const float*)d_in[4];
    const float* b1   = (const float*)d_in[5];
    const float* W2   = (const float*)d_in[6];
    const float* b2   = (const float*)d_in[7];
    const float* Wlin = (const float*)d_in[8];
    const float* blin = (const float*)d_in[9];
    float* out = (float*)d_out;

    char* ws = (char*)d_ws;
    size_t off = 0;
    auto carve = [&](size_t bytes) -> void* {
        void* p = ws + off;
        off = (off + bytes + 255) & ~(size_t)255;
        return p;
    };
    int*   gcur = (int*)  carve(NBB * sizeof(int));
    float* dinv = (float*)carve(N_NODES * sizeof(float));
    int2*  tmp  = (int2*) carve((size_t)NBB * CAPB * sizeof(int2));   // 8.1 MB
    unsigned int* hbf = (unsigned int*)carve((size_t)N_NODES * 64 * sizeof(unsigned int));
    float* agg  = (float*)carve((size_t)N_NODES * C * sizeof(float));

    const int NB_A = (N_EDGES + CHUNK - 1) / CHUNK;   // 196
    const int NB_G = (N_NODES + 63) / 64;             // 782

    hipMemsetAsync(gcur, 0, NBB * sizeof(int), stream);

    // edge partition + degrees
    k_binA<<<NB_A, 256, 0, stream>>>(ei, gcur, tmp);
    k_dinv<<<NBB, 256, 0, stream>>>(tmp, gcur, dinv);

    // Layer 1
    k_gemm<false><<<NB_G, 256, 0, stream>>>(x, W1, hbf);
    k_agg<false><<<NBB, 512, 0, stream>>>((const uint4*)hbf, tmp, gcur, dinv,
                                          b1, Wlin, blin, agg);
    // Layer 2
    k_gemm<true><<<NB_G, 256, 0, stream>>>(agg, W2, hbf);
    k_agg<true><<<NBB, 512, 0, stream>>>((const uint4*)hbf, tmp, gcur, dinv,
                                         b2, Wlin, blin, out);
}

// Round 6
// 239.421 us; speedup vs baseline: 1.0741x; 1.0741x over previous
//
#include <hip/hip_runtime.h>
#include <hip/hip_bf16.h>

#define N_NODES 50000
#define N_EDGES 800000
#define C 128

#define NBB   391      // buckets of 128 nodes: bucket = dst >> 7
#define CAPB  2600     // per-bucket capacity (mean 2046, +12 sigma)
#define CHUNK 2048     // edges per binA block

// ---------------------------------------------------------------------------
// k_binA: single-level radix partition. Each block takes CHUNK edges,
// histograms by bucket (dst>>7) in LDS, scatters locally in LDS, reserves a
// per-bucket run with ONE global atomic per bucket, writes runs coalesced
// into tmp (bucket-strided: bucket b owns [b*CAPB, (b+1)*CAPB)).
// ---------------------------------------------------------------------------
__global__ __launch_bounds__(256) void k_binA(const int* __restrict__ ei,
                                              int* __restrict__ gcur,
                                              int2* __restrict__ tmp) {
    __shared__ int hist[NBB];
    __shared__ int lbase[NBB];
    __shared__ int gbaseL[NBB];
    __shared__ int stmp[256];
    __shared__ int2 buf[CHUNK];
    __shared__ int totalv;

    int tid = threadIdx.x;
    int e0 = blockIdx.x * CHUNK;

    for (int i = tid; i < NBB; i += 256) hist[i] = 0;
    __syncthreads();

    int sarr[8], darr[8], parr[8];
#pragma unroll
    for (int j = 0; j < 8; ++j) {
        int e = e0 + j * 256 + tid;
        darr[j] = -1;
        if (e < N_EDGES) {
            sarr[j] = ei[e];
            int d = ei[N_EDGES + e];
            darr[j] = d;
            parr[j] = atomicAdd(&hist[d >> 7], 1);
        }
    }
    __syncthreads();

    // exclusive scan of hist (pairs: thread t owns buckets 2t, 2t+1)
    {
        int i0 = 2 * tid, i1 = 2 * tid + 1;
        int c0 = (i0 < NBB) ? hist[i0] : 0;
        int c1 = (i1 < NBB) ? hist[i1] : 0;
        int c = c0 + c1;
        stmp[tid] = c;
        __syncthreads();
        int v = c;
        for (int d = 1; d < 256; d <<= 1) {
            int w = (tid >= d) ? stmp[tid - d] : 0;
            __syncthreads();
            v += w;
            stmp[tid] = v;
            __syncthreads();
        }
        int excl = v - c;
        if (i0 < NBB) lbase[i0] = excl;
        if (i1 < NBB) lbase[i1] = excl + c0;
        if (tid == 255) totalv = v;
    }
    // reserve global runs (one atomic per non-empty bucket per block)
    for (int i = tid; i < NBB; i += 256) {
        int cnt = hist[i];
        int run = (cnt > 0) ? atomicAdd(&gcur[i], cnt) : 0;
        gbaseL[i] = i * CAPB + run;
    }
    __syncthreads();

    // LDS scatter
#pragma unroll
    for (int j = 0; j < 8; ++j) {
        if (darr[j] >= 0) {
            int b = darr[j] >> 7;
            buf[lbase[b] + parr[j]] = make_int2(sarr[j], darr[j]);
        }
    }
    __syncthreads();

    // coalesced write-out of per-bucket runs
    int total = totalv;
    for (int i = tid; i < total; i += 256) {
        int2 v = buf[i];
        int b = v.y >> 7;
        int gpos = gbaseL[b] + (i - lbase[b]);
        if (gpos < (b + 1) * CAPB) tmp[gpos] = v;   // overflow safety
    }
}

// ---------------------------------------------------------------------------
// k_dinv: per-node in-degree from the bucket, write dinv = rsqrt(deg+1).
// ---------------------------------------------------------------------------
__global__ __launch_bounds__(256) void k_dinv(const int2* __restrict__ tmp,
                                              const int* __restrict__ gcur,
                                              float* __restrict__ dinv) {
    __shared__ int cnt[128];
    int b = blockIdx.x, tid = threadIdx.x;
    if (tid < 128) cnt[tid] = 0;
    __syncthreads();
    int n = gcur[b];
    if (n > CAPB) n = CAPB;
    for (int i = tid; i < n; i += 256)
        atomicAdd(&cnt[tmp[b * CAPB + i].y & 127], 1);
    __syncthreads();
    int node = b * 128 + tid;
    if (tid < 128 && node < N_NODES)
        dinv[node] = rsqrtf((float)cnt[tid] + 1.0f);
}

// ---------------------------------------------------------------------------
// bf16 pack helpers (RTN)
// ---------------------------------------------------------------------------
__device__ __forceinline__ unsigned int bf16rtn(float f) {
    unsigned int u = __float_as_uint(f);
    return (u + 0x7fffu + ((u >> 16) & 1u)) >> 16;
}
__device__ __forceinline__ unsigned int packbf2(float lo, float hi) {
    return bf16rtn(lo) | (bf16rtn(hi) << 16);
}

// ---------------------------------------------------------------------------
// f32 GEMM -> PRE-SCALED bf16 out: Hout[r] = dinv[r] * (A[r] @ W)  (bf16)
// 64x128 tile, 256 thr, K-panels of 32 in LDS, per-thread 4 rows x 8 cols.
// ---------------------------------------------------------------------------
#define XS_STRIDE 44

template <bool RELU>
__global__ __launch_bounds__(256, 2) void k_gemm(const float* __restrict__ A,
                                                 const float* __restrict__ W,
                                                 const float* __restrict__ dinv,
                                                 unsigned int* __restrict__ Hout) {
    __shared__ float Wp[32 * 128];
    __shared__ float Xs[64 * XS_STRIDE];
    int tid = threadIdx.x;
    int cg = tid & 15;
    int rg = tid >> 4;
    int row0 = blockIdx.x * 64;

    const float4* W4 = (const float4*)W;
    const float4* A4 = (const float4*)A;
    float4* Wp4 = (float4*)Wp;

    float4 acc[4][2];
#pragma unroll
    for (int i = 0; i < 4; ++i) {
        acc[i][0] = make_float4(0.f, 0.f, 0.f, 0.f);
        acc[i][1] = make_float4(0.f, 0.f, 0.f, 0.f);
    }

    for (int p = 0; p < 4; ++p) {
        if (p) __syncthreads();
#pragma unroll
        for (int i = 0; i < 4; ++i)
            Wp4[tid + 256 * i] = W4[p * 1024 + tid + 256 * i];
#pragma unroll
        for (int i = 0; i < 2; ++i) {
            int idx = tid + 256 * i;
            int r = idx >> 3, c4 = idx & 7;
            int gr = row0 + r;
            float4 v = make_float4(0.f, 0.f, 0.f, 0.f);
            if (gr < N_NODES) v = A4[gr * 32 + p * 8 + c4];
            if (RELU) {
                v.x = fmaxf(v.x, 0.f); v.y = fmaxf(v.y, 0.f);
                v.z = fmaxf(v.z, 0.f); v.w = fmaxf(v.w, 0.f);
            }
            *(float4*)(Xs + r * XS_STRIDE + c4 * 4) = v;
        }
        __syncthreads();

#pragma unroll
        for (int k0 = 0; k0 < 32; k0 += 4) {
            float4 wv[4][2];
#pragma unroll
            for (int kk = 0; kk < 4; ++kk) {
                wv[kk][0] = Wp4[(k0 + kk) * 32 + cg];
                wv[kk][1] = Wp4[(k0 + kk) * 32 + 16 + cg];
            }
            float4 xv[4];
#pragma unroll
            for (int i = 0; i < 4; ++i)
                xv[i] = *(const float4*)(Xs + (rg * 4 + i) * XS_STRIDE + k0);
#pragma unroll
            for (int i = 0; i < 4; ++i) {
#pragma unroll
                for (int kk = 0; kk < 4; ++kk) {
                    float xs = (kk == 0) ? xv[i].x : (kk == 1) ? xv[i].y
                             : (kk == 2) ? xv[i].z : xv[i].w;
#pragma unroll
                    for (int h = 0; h < 2; ++h) {
                        acc[i][h].x += xs * wv[kk][h].x;
                        acc[i][h].y += xs * wv[kk][h].y;
                        acc[i][h].z += xs * wv[kk][h].z;
                        acc[i][h].w += xs * wv[kk][h].w;
                    }
                }
            }
        }
    }

#pragma unroll
    for (int i = 0; i < 4; ++i) {
        int gr = row0 + rg * 4 + i;
        if (gr < N_NODES) {
            float dv = dinv[gr];
            uint2 u0, u1;
            u0.x = packbf2(dv * acc[i][0].x, dv * acc[i][0].y);
            u0.y = packbf2(dv * acc[i][0].z, dv * acc[i][0].w);
            u1.x = packbf2(dv * acc[i][1].x, dv * acc[i][1].y);
            u1.y = packbf2(dv * acc[i][1].z, dv * acc[i][1].w);
            *(uint2*)&Hout[gr * 64 + cg * 2]      = u0;
            *(uint2*)&Hout[gr * 64 + 32 + cg * 2] = u1;
        }
    }
}

// ---------------------------------------------------------------------------
// Fused bucket aggregation: block = 1024 thr (16 waves) per 128-node bucket.
// Stage bucket edges from tmp into LDS, build block-local CSR, then each
// wave aggregates 8 nodes. h is PRE-SCALED (dinv[s]*h[s]) so the gather is
// a pure row-sum; self-term folds in post-combine; one dv mul at the end.
// FINAL fuses relu + 128->1 linear.
// ---------------------------------------------------------------------------
__device__ __forceinline__ void add8(float* acc, uint4 u) {
    acc[0] += __uint_as_float(u.x << 16);
    acc[1] += __uint_as_float(u.x & 0xffff0000u);
    acc[2] += __uint_as_float(u.y << 16);
    acc[3] += __uint_as_float(u.y & 0xffff0000u);
    acc[4] += __uint_as_float(u.z << 16);
    acc[5] += __uint_as_float(u.z & 0xffff0000u);
    acc[6] += __uint_as_float(u.w << 16);
    acc[7] += __uint_as_float(u.w & 0xffff0000u);
}

template <bool FINAL>
__global__ __launch_bounds__(1024) void k_agg(const uint4* __restrict__ h4,
                                              const int2* __restrict__ tmp,
                                              const int* __restrict__ gcur,
                                              const float* __restrict__ bias,
                                              const float* __restrict__ Wlin,
                                              const float* __restrict__ blin,
                                              float* __restrict__ aggout) {
    __shared__ int   rawsrc[CAPB];
    __shared__ short rawloc[CAPB];
    __shared__ int   lcsr[CAPB];
    __shared__ int   lcnt[128];
    __shared__ int   lbase0[128];
    __shared__ int   lcur[128];
    __shared__ int   stmp[128];

    int b = blockIdx.x, tid = threadIdx.x;
    int cnt = gcur[b];
    if (cnt > CAPB) cnt = CAPB;

    if (tid < 128) { lcnt[tid] = 0; lcur[tid] = 0; }
    __syncthreads();

    for (int i = tid; i < cnt; i += 1024) {
        int2 v = tmp[b * CAPB + i];
        int l = v.y & 127;
        rawsrc[i] = v.x;
        rawloc[i] = (short)l;
        atomicAdd(&lcnt[l], 1);
    }
    __syncthreads();

    // exclusive scan of lcnt -> lbase0 (Hillis-Steele over 128)
    {
        int c = (tid < 128) ? lcnt[tid] : 0;
        if (tid < 128) stmp[tid] = c;
        __syncthreads();
        int v = c;
        for (int d = 1; d < 128; d <<= 1) {
            int w = (tid >= d && tid < 128) ? stmp[tid - d] : 0;
            __syncthreads();
            if (tid < 128) { v += w; stmp[tid] = v; }
            __syncthreads();
        }
        if (tid < 128) lbase0[tid] = v - c;
    }
    __syncthreads();

    for (int i = tid; i < cnt; i += 1024) {
        int l = rawloc[i];
        int p = atomicAdd(&lcur[l], 1);
        lcsr[lbase0[l] + p] = rawsrc[i];
    }
    __syncthreads();

    int wv = tid >> 6, lane = tid & 63, eg = lane >> 4, cq = lane & 15;

    // hoisted per-lane constants
    float4 bv0 = ((const float4*)bias)[cq * 2];
    float4 bv1 = ((const float4*)bias)[cq * 2 + 1];
    float4 wl0 = make_float4(0.f, 0.f, 0.f, 0.f), wl1 = wl0;
    float bl = 0.f;
    if (FINAL) {
        wl0 = ((const float4*)Wlin)[cq * 2];
        wl1 = ((const float4*)Wlin)[cq * 2 + 1];
        bl = blin[0];
    }

#pragma unroll 1
    for (int t = 0; t < 8; ++t) {
        int ln = wv * 8 + t;
        int node = b * 128 + ln;
        if (node >= N_NODES) break;   // uniform per wave
        int deg = lcnt[ln];
        int o0 = lbase0[ln], o1 = o0 + deg;

        float acc[8];
#pragma unroll
        for (int j = 0; j < 8; ++j) acc[j] = 0.f;

        int e = o0;
        for (; e + 8 <= o1; e += 8) {
            int s0 = lcsr[e + 2 * eg];
            int s1 = lcsr[e + 2 * eg + 1];
            uint4 u0 = h4[s0 * 16 + cq];
            uint4 u1 = h4[s1 * 16 + cq];
            add8(acc, u0);
            add8(acc, u1);
        }
        {   // tail (< 8 edges): group eg takes e+2eg, e+2eg+1 if in range
            int r = o1 - e;
            int b0 = e + 2 * eg;
            if (2 * eg < r)     { int s = lcsr[b0];     add8(acc, h4[s * 16 + cq]); }
            if (2 * eg + 1 < r) { int s = lcsr[b0 + 1]; add8(acc, h4[s * 16 + cq]); }
        }
        // combine edge groups
#pragma unroll
        for (int j = 0; j < 8; ++j) {
            acc[j] += __shfl_xor(acc[j], 16, 64);
            acc[j] += __shfl_xor(acc[j], 32, 64);
        }

        // self-term (pre-scaled row) + final dv multiply + bias
        float dv = rsqrtf((float)deg + 1.0f);
        uint4 us = h4[node * 16 + cq];
        float hv[8];
        hv[0] = __uint_as_float(us.x << 16); hv[1] = __uint_as_float(us.x & 0xffff0000u);
        hv[2] = __uint_as_float(us.y << 16); hv[3] = __uint_as_float(us.y & 0xffff0000u);
        hv[4] = __uint_as_float(us.z << 16); hv[5] = __uint_as_float(us.z & 0xffff0000u);
        hv[6] = __uint_as_float(us.w << 16); hv[7] = __uint_as_float(us.w & 0xffff0000u);
        float o[8];
        o[0] = dv * (acc[0] + hv[0]) + bv0.x;
        o[1] = dv * (acc[1] + hv[1]) + bv0.y;
        o[2] = dv * (acc[2] + hv[2]) + bv0.z;
        o[3] = dv * (acc[3] + hv[3]) + bv0.w;
        o[4] = dv * (acc[4] + hv[4]) + bv1.x;
        o[5] = dv * (acc[5] + hv[5]) + bv1.y;
        o[6] = dv * (acc[6] + hv[6]) + bv1.z;
        o[7] = dv * (acc[7] + hv[7]) + bv1.w;

        if (!FINAL) {
            if (eg == 0) {
                float4* out4 = (float4*)aggout;
                out4[node * 32 + cq * 2]     = make_float4(o[0], o[1], o[2], o[3]);
                out4[node * 32 + cq * 2 + 1] = make_float4(o[4], o[5], o[6], o[7]);
            }
        } else {
            float v = fmaxf(o[0], 0.f) * wl0.x + fmaxf(o[1], 0.f) * wl0.y
                    + fmaxf(o[2], 0.f) * wl0.z + fmaxf(o[3], 0.f) * wl0.w
                    + fmaxf(o[4], 0.f) * wl1.x + fmaxf(o[5], 0.f) * wl1.y
                    + fmaxf(o[6], 0.f) * wl1.z + fmaxf(o[7], 0.f) * wl1.w;
            v += __shfl_xor(v, 1, 64);
            v += __shfl_xor(v, 2, 64);
            v += __shfl_xor(v, 4, 64);
            v += __shfl_xor(v, 8, 64);
            if (lane == 0) aggout[node] = v + bl;
        }
    }
}

// ---------------------------------------------------------------------------
extern "C" void kernel_launch(void* const* d_in, const int* in_sizes, int n_in,
                              void* d_out, int out_size, void* d_ws, size_t ws_size,
                              hipStream_t stream) {
    const float* x    = (const float*)d_in[0];
    const int*   ei   = (const int*)d_in[2];
    const float* W1   = (const float*)d_in[4];
    const float* b1   = (const float*)d_in[5];
    const float* W2   = (const float*)d_in[6];
    const float* b2   = (const float*)d_in[7];
    const float* Wlin = (const float*)d_in[8];
    const float* blin = (const float*)d_in[9];
    float* out = (float*)d_out;

    char* ws = (char*)d_ws;
    size_t off = 0;
    auto carve = [&](size_t bytes) -> void* {
        void* p = ws + off;
        off = (off + bytes + 255) & ~(size_t)255;
        return p;
    };
    int*   gcur = (int*)  carve(NBB * sizeof(int));
    float* dinv = (float*)carve(N_NODES * sizeof(float));
    int2*  tmp  = (int2*) carve((size_t)NBB * CAPB * sizeof(int2));   // 8.1 MB
    unsigned int* hbf = (unsigned int*)carve((size_t)N_NODES * 64 * sizeof(unsigned int));
    float* agg  = (float*)carve((size_t)N_NODES * C * sizeof(float));

    const int NB_A = (N_EDGES + CHUNK - 1) / CHUNK;   // 391
    const int NB_G = (N_NODES + 63) / 64;             // 782

    hipMemsetAsync(gcur, 0, NBB * sizeof(int), stream);

    // edge partition + degrees
    k_binA<<<NB_A, 256, 0, stream>>>(ei, gcur, tmp);
    k_dinv<<<NBB, 256, 0, stream>>>(tmp, gcur, dinv);

    // Layer 1 (h pre-scaled by dinv[row])
    k_gemm<false><<<NB_G, 256, 0, stream>>>(x, W1, dinv, hbf);
    k_agg<false><<<NBB, 1024, 0, stream>>>((const uint4*)hbf, tmp, gcur,
                                           b1, Wlin, blin, agg);
    // Layer 2
    k_gemm<true><<<NB_G, 256, 0, stream>>>(agg, W2, dinv, hbf);
    k_agg<true><<<NBB, 1024, 0, stream>>>((const uint4*)hbf, tmp, gcur,
                                          b2, Wlin, blin, out);
}